// Round 3
// baseline (128.718 us; speedup 1.0000x reference)
//
#include <hip/hip_runtime.h>
#include <hip/hip_bf16.h>

#define DIM 1024
#define NBLK 1024          // grid size; 4 blocks/CU -> always co-resident
#define MAGIC 0x5A17C0DEu  // != 0xAAAAAAAA poison

// ws layout: [0,4KB) flags[NBLK] (u32) | [4KB,8KB) qpart[513] (f32) | [8KB,...) escore[n_ent]
//
// Single fused kernel.
//  Phase P (all blocks): grid-stride over row-chunks (4 rows, 1 wave/row):
//    rows [0,n_ent)        escore[row] = ent[row] . Ws[D:]
//    rows [n_ent,n_ent+2D) qpart contribution: c[k]*(Wq[k] . Ws[:D]), c=cat(ent[s],rel[r])
//    row  n_ent+2D         bq . Ws[:D]
//  Publish: threadfence + agent-scope flag[bid]=MAGIC.
//  Phase S (blocks < nscore): spin until all flags MAGIC (replay-safe: stale
//  MAGIC is harmless since recomputed values are bitwise identical), reduce
//  qpart -> q_term, out[i] = sigmoid(q_term + escore[cand[i]] + bs).
__global__ __launch_bounds__(256, 4)
void k_fused(const int* __restrict__ subject,
             const int* __restrict__ relation,
             const int* __restrict__ cand,
             const float* __restrict__ ent,
             const float* __restrict__ rel,
             const float* __restrict__ Wq,
             const float* __restrict__ bq,
             const float* __restrict__ Ws,
             const float* __restrict__ bs,
             float* __restrict__ out,
             unsigned int* __restrict__ flags,
             float* __restrict__ qpart,
             float* __restrict__ escore,
             int n_ent, int n_cand, int nrb, int qrb0, int nq) {
    const int bid  = blockIdx.x;
    const int tid  = threadIdx.x;
    const int wid  = tid >> 6;
    const int lane = tid & 63;
    const int nscore = (n_cand + 255) / 256;

    // Prefetch this thread's candidate (consumed in phase S).
    int my_cand = 0;
    const int out_i = bid * 256 + tid;
    if (bid < nscore && out_i < n_cand) my_cand = cand[out_i];

    // Ws slices held in registers (same lane->offset map for every row).
    float4 ws1[4], ws2[4];
#pragma unroll
    for (int it = 0; it < 4; ++it) {
        const int j = (it * 64 + lane) * 4;
        ws1[it] = *(const float4*)(Ws + j);
        ws2[it] = *(const float4*)(Ws + DIM + j);
    }
    const int s = subject[0];
    const int r = relation[0];

    __shared__ float sp[4];
    __shared__ float s_q;

    // ---- phase P: prep chunks (reverse map so light tail lands on consumers) ----
    for (int rb = (NBLK - 1) - bid; rb < nrb; rb += NBLK) {
        const int row = rb * 4 + wid;
        float acc = 0.f;
        float qv  = 0.f;
        bool  isq = false;
        if (row < n_ent) {
            const float* rp = ent + (size_t)row * DIM;
#pragma unroll
            for (int it = 0; it < 4; ++it) {
                const int j = (it * 64 + lane) * 4;
                float4 a = *(const float4*)(rp + j);
                acc += a.x * ws2[it].x + a.y * ws2[it].y + a.z * ws2[it].z + a.w * ws2[it].w;
            }
#pragma unroll
            for (int off = 32; off; off >>= 1) acc += __shfl_down(acc, off, 64);
            if (lane == 0) escore[row] = acc;
        } else if (row < n_ent + 2 * DIM) {
            isq = true;
            const int k = row - n_ent;
            const float c = (k < DIM) ? ent[(size_t)s * DIM + k]
                                      : rel[(size_t)r * DIM + (k - DIM)];
            const float* rp = Wq + (size_t)k * DIM;
#pragma unroll
            for (int it = 0; it < 4; ++it) {
                const int j = (it * 64 + lane) * 4;
                float4 a = *(const float4*)(rp + j);
                acc += a.x * ws1[it].x + a.y * ws1[it].y + a.z * ws1[it].z + a.w * ws1[it].w;
            }
#pragma unroll
            for (int off = 32; off; off >>= 1) acc += __shfl_down(acc, off, 64);
            qv = acc * c;
        } else if (row == n_ent + 2 * DIM) {
            isq = true;
#pragma unroll
            for (int it = 0; it < 4; ++it) {
                const int j = (it * 64 + lane) * 4;
                float4 a = *(const float4*)(bq + j);
                acc += a.x * ws1[it].x + a.y * ws1[it].y + a.z * ws1[it].z + a.w * ws1[it].w;
            }
#pragma unroll
            for (int off = 32; off; off >>= 1) acc += __shfl_down(acc, off, 64);
            qv = acc;
        }
        if (rb >= qrb0) {                 // q-chunk: block sum -> qpart (block-uniform branch)
            if (lane == 0) sp[wid] = isq ? qv : 0.f;
            __syncthreads();
            if (tid == 0) qpart[rb - qrb0] = sp[0] + sp[1] + sp[2] + sp[3];
            __syncthreads();
        }
    }

    // ---- publish ----
    __syncthreads();
    __threadfence();                       // drain this block's stores to coherent point
    if (tid == 0)
        __hip_atomic_store(&flags[bid], MAGIC, __ATOMIC_RELAXED, __HIP_MEMORY_SCOPE_AGENT);

    if (bid >= nscore) return;

    // ---- phase S: wait for all producers ----
    if (wid == 0) {
        for (;;) {
            int ok = 1;
            for (int f = lane; f < NBLK; f += 64)
                if (__hip_atomic_load(&flags[f], __ATOMIC_RELAXED, __HIP_MEMORY_SCOPE_AGENT) != MAGIC)
                    ok = 0;
            if (__all(ok)) break;
            __builtin_amdgcn_s_sleep(8);
        }
    }
    __syncthreads();
    __threadfence();                       // acquire: see producers' escore/qpart

    if (wid == 0) {
        float v = 0.f;
        for (int i = lane; i < nq; i += 64) v += qpart[i];   // fixed order: deterministic
#pragma unroll
        for (int off = 32; off; off >>= 1) v += __shfl_down(v, off, 64);
        if (lane == 0) s_q = v + bs[0];
    }
    __syncthreads();

    if (out_i < n_cand) {
        const float x = s_q + escore[my_cand];
        out[out_i] = 1.f / (1.f + expf(-x));
    }
}

extern "C" void kernel_launch(void* const* d_in, const int* in_sizes, int n_in,
                              void* d_out, int out_size, void* d_ws, size_t ws_size,
                              hipStream_t stream) {
    const int*   subject  = (const int*)d_in[0];
    const int*   relation = (const int*)d_in[1];
    const int*   cand     = (const int*)d_in[2];
    const float* ent      = (const float*)d_in[3];
    const float* rel      = (const float*)d_in[4];
    const float* Wq       = (const float*)d_in[5];
    const float* bq       = (const float*)d_in[6];
    const float* Ws       = (const float*)d_in[7];
    const float* bs       = (const float*)d_in[8];

    const int n_ent  = in_sizes[3] / DIM;            // 10000
    const int n_cand = in_sizes[2];                  // 131072

    unsigned int* flags = (unsigned int*)d_ws;       // NBLK u32
    float* qpart  = (float*)((char*)d_ws + 4096);    // 513 f32
    float* escore = (float*)((char*)d_ws + 8192);    // n_ent f32

    const int erb  = n_ent / 4;                      // 2500 (n_ent % 4 == 0)
    const int nrb  = erb + (2 * DIM) / 4 + 1;        // 3013 row-chunks
    const int nq   = (2 * DIM) / 4 + 1;              // 513 q partials

    k_fused<<<NBLK, 256, 0, stream>>>(subject, relation, cand, ent, rel, Wq, bq,
                                      Ws, bs, (float*)d_out, flags, qpart, escore,
                                      n_ent, n_cand, nrb, erb, nq);
}

// Round 4
// 24.298 us; speedup vs baseline: 5.2974x; 5.2974x over previous
//
#include <hip/hip_runtime.h>
#include <hip/hip_bf16.h>

#define DIM 1024
#define NBLK 1024          // 4 blocks/CU on 256 CUs -> always co-resident
#define MAGIC 0x5A17C0DEu  // != 0xAAAAAAAA poison, != 0

// Agent-scope relaxed atomics: sc1 write-through / cache-bypassing loads.
// No dirty L2 lines are ever created for cross-block data => no threadfence
// (buffer_wbl2 / buffer_inv L2 tag-walks) is needed anywhere.
__device__ __forceinline__ void st_ag(float* p, float v) {
    __hip_atomic_store(p, v, __ATOMIC_RELAXED, __HIP_MEMORY_SCOPE_AGENT);
}
__device__ __forceinline__ float ld_ag(const float* p) {
    return __hip_atomic_load(p, __ATOMIC_RELAXED, __HIP_MEMORY_SCOPE_AGENT);
}
__device__ __forceinline__ void st_agu(unsigned* p, unsigned v) {
    __hip_atomic_store(p, v, __ATOMIC_RELAXED, __HIP_MEMORY_SCOPE_AGENT);
}
__device__ __forceinline__ unsigned ld_agu(const unsigned* p) {
    return __hip_atomic_load(p, __ATOMIC_RELAXED, __HIP_MEMORY_SCOPE_AGENT);
}

// ws layout: [0,4K) flags[NBLK] | [4K) ready | [4K+4) q_total | [8K) qpart[513] | [16K) escore[n_ent]
//
// Phase P (all 1024 blocks), reverse-mapped grid-stride over 4-row chunks:
//   rows [0,n_ent)        escore[row] = ent[row] . Ws[D:]
//   rows [n_ent,n_ent+2D) qpart chunk sum of c[k]*(Wq[k] . Ws[:D]), c=cat(ent[s],rel[r])
//   row  n_ent+2D         bq . Ws[:D]
// Publish flag[bid]=MAGIC (relaxed agent; prior sc1 stores drained by the
// pre-barrier vmcnt(0) + explicit waitcnt).
// Aggregator (bid NBLK-1): poll all flags -> reduce qpart -> q_total -> ready.
// Consumers (bid < 512): spin on the single ready word, then
// out[i] = sigmoid(q_total + escore[cand[i]]).  Replay-safe: stale MAGIC only
// short-circuits waiting on bitwise-identical recomputed values.
__global__ __launch_bounds__(256, 4)
void k_fused(const int* __restrict__ subject,
             const int* __restrict__ relation,
             const int* __restrict__ cand,
             const float* __restrict__ ent,
             const float* __restrict__ rel,
             const float* __restrict__ Wq,
             const float* __restrict__ bq,
             const float* __restrict__ Ws,
             const float* __restrict__ bs,
             float* __restrict__ out,
             unsigned* __restrict__ flags,
             unsigned* __restrict__ ready,
             float* __restrict__ q_total,
             float* __restrict__ qpart,
             float* __restrict__ escore,
             int n_ent, int n_cand, int nrb, int qrb0, int nq) {
    const int bid  = blockIdx.x;
    const int tid  = threadIdx.x;
    const int wid  = tid >> 6;
    const int lane = tid & 63;
    const int nscore = (n_cand + 255) / 256;       // 512

    // Prefetch this thread's candidate (used in phase S).
    int my_cand = 0;
    const int out_i = bid * 256 + tid;
    if (bid < nscore && out_i < n_cand) my_cand = cand[out_i];

    // Ws slices in registers (lane->offset map identical for every row).
    float4 ws1[4], ws2[4];
#pragma unroll
    for (int it = 0; it < 4; ++it) {
        const int j = (it * 64 + lane) * 4;
        ws1[it] = *(const float4*)(Ws + j);
        ws2[it] = *(const float4*)(Ws + DIM + j);
    }
    const int s = subject[0];
    const int r = relation[0];

    __shared__ float sp[4];
    __shared__ float s_q;

    // ---- phase P ----
    for (int rb = (NBLK - 1) - bid; rb < nrb; rb += NBLK) {
        const int row = rb * 4 + wid;
        float acc = 0.f, qv = 0.f;
        bool isq = false;
        if (row < n_ent) {
            const float* rp = ent + (size_t)row * DIM;
#pragma unroll
            for (int it = 0; it < 4; ++it) {
                const int j = (it * 64 + lane) * 4;
                float4 a = *(const float4*)(rp + j);
                acc += a.x * ws2[it].x + a.y * ws2[it].y + a.z * ws2[it].z + a.w * ws2[it].w;
            }
#pragma unroll
            for (int off = 32; off; off >>= 1) acc += __shfl_down(acc, off, 64);
            if (lane == 0) st_ag(&escore[row], acc);
        } else if (row < n_ent + 2 * DIM) {
            isq = true;
            const int k = row - n_ent;
            const float c = (k < DIM) ? ent[(size_t)s * DIM + k]
                                      : rel[(size_t)r * DIM + (k - DIM)];
            const float* rp = Wq + (size_t)k * DIM;
#pragma unroll
            for (int it = 0; it < 4; ++it) {
                const int j = (it * 64 + lane) * 4;
                float4 a = *(const float4*)(rp + j);
                acc += a.x * ws1[it].x + a.y * ws1[it].y + a.z * ws1[it].z + a.w * ws1[it].w;
            }
#pragma unroll
            for (int off = 32; off; off >>= 1) acc += __shfl_down(acc, off, 64);
            qv = acc * c;
        } else if (row == n_ent + 2 * DIM) {
            isq = true;
#pragma unroll
            for (int it = 0; it < 4; ++it) {
                const int j = (it * 64 + lane) * 4;
                float4 a = *(const float4*)(bq + j);
                acc += a.x * ws1[it].x + a.y * ws1[it].y + a.z * ws1[it].z + a.w * ws1[it].w;
            }
#pragma unroll
            for (int off = 32; off; off >>= 1) acc += __shfl_down(acc, off, 64);
            qv = acc;
        }
        if (rb >= qrb0) {                          // block-uniform branch
            if (lane == 0) sp[wid] = isq ? qv : 0.f;
            __syncthreads();
            if (tid == 0) st_ag(&qpart[rb - qrb0], sp[0] + sp[1] + sp[2] + sp[3]);
            __syncthreads();
        }
    }

    // ---- publish (no fence: sc1 stores complete at coherent point) ----
    __syncthreads();                               // each wave drains vmcnt(0) at barrier
    if (tid == 0) {
        asm volatile("s_waitcnt vmcnt(0)" ::: "memory");
        st_agu(&flags[bid], MAGIC);
    }

    // ---- aggregator ----
    if (bid == NBLK - 1) {
        if (wid == 0) {
            for (;;) {
                int ok = 1;
                for (int f = lane; f < NBLK; f += 64)
                    if (ld_agu(&flags[f]) != MAGIC) ok = 0;
                if (__all(ok)) break;
                __builtin_amdgcn_s_sleep(8);
            }
            float v = 0.f;
            for (int i = lane; i < nq; i += 64) v += ld_ag(&qpart[i]);  // fixed order
#pragma unroll
            for (int off = 32; off; off >>= 1) v += __shfl_down(v, off, 64);
            if (lane == 0) {
                st_ag(q_total, v + bs[0]);
                asm volatile("s_waitcnt vmcnt(0)" ::: "memory");
                st_agu(ready, MAGIC);
            }
        }
        return;
    }
    if (bid >= nscore) return;

    // ---- phase S: spin on the single ready word ----
    if (tid == 0) {
        while (ld_agu(ready) != MAGIC) __builtin_amdgcn_s_sleep(16);
        s_q = ld_ag(q_total);
    }
    __syncthreads();

    if (out_i < n_cand) {
        const float e = ld_ag(&escore[my_cand]);
        const float x = s_q + e;
        out[out_i] = 1.f / (1.f + expf(-x));
    }
}

extern "C" void kernel_launch(void* const* d_in, const int* in_sizes, int n_in,
                              void* d_out, int out_size, void* d_ws, size_t ws_size,
                              hipStream_t stream) {
    const int*   subject  = (const int*)d_in[0];
    const int*   relation = (const int*)d_in[1];
    const int*   cand     = (const int*)d_in[2];
    const float* ent      = (const float*)d_in[3];
    const float* rel      = (const float*)d_in[4];
    const float* Wq       = (const float*)d_in[5];
    const float* bq       = (const float*)d_in[6];
    const float* Ws       = (const float*)d_in[7];
    const float* bs       = (const float*)d_in[8];

    const int n_ent  = in_sizes[3] / DIM;            // 10000
    const int n_cand = in_sizes[2];                  // 131072

    char* ws = (char*)d_ws;
    unsigned* flags   = (unsigned*)ws;               // NBLK u32
    unsigned* ready   = (unsigned*)(ws + 4096);
    float*    q_total = (float*)(ws + 4096 + 4);
    float*    qpart   = (float*)(ws + 8192);         // 513 f32
    float*    escore  = (float*)(ws + 16384);        // n_ent f32

    const int erb = n_ent / 4;                       // 2500 (n_ent % 4 == 0)
    const int nrb = erb + (2 * DIM) / 4 + 1;         // 3013 row-chunks
    const int nq  = (2 * DIM) / 4 + 1;               // 513 q partials

    k_fused<<<NBLK, 256, 0, stream>>>(subject, relation, cand, ent, rel, Wq, bq,
                                      Ws, bs, (float*)d_out, flags, ready, q_total,
                                      qpart, escore, n_ent, n_cand, nrb, erb, nq);
}

// Round 5
// 18.944 us; speedup vs baseline: 6.7948x; 1.2827x over previous
//
#include <hip/hip_runtime.h>
#include <hip/hip_bf16.h>

#define DIM 1024
#define NQ 2049            // 2048 per-row q partials + 1 bias partial

// Row space (2 rows = 1 pair per 64-lane wave, 4 waves/block):
//   rows [0, n_ent)        : escore[row] = ent[row] . Ws[D:]
//   rows [n_ent, n_ent+2D) : k = row-n_ent; qpart[k] = c[k]*(Wq[k] . Ws[:D]),
//                            c = cat(ent[s], rel[r])
//   row  n_ent+2D          : qpart[2048] = bq . Ws[:D]
// n_ent (10000) and 2D (2048) are even -> pairs never straddle categories
// or the k<1024 / k>=1024 split.
__global__ void k_prep(const int* __restrict__ subject,
                       const int* __restrict__ relation,
                       const float* __restrict__ ent,
                       const float* __restrict__ rel,
                       const float* __restrict__ Wq,
                       const float* __restrict__ bq,
                       const float* __restrict__ Ws,
                       float* __restrict__ qpart,
                       float* __restrict__ escore,
                       int n_ent, int nrows, int npairs) {
    const int wid  = threadIdx.x >> 6;
    const int lane = threadIdx.x & 63;
    const int pair = blockIdx.x * 4 + wid;
    if (pair >= npairs) return;

    const int row0 = pair * 2;
    const int row1 = row0 + 1;
    const bool is_ent = (row0 < n_ent);

    // Row base pointers + per-row output multipliers.
    const float* rp0;
    const float* rp1;
    float m0 = 1.f, m1 = 1.f;
    if (is_ent) {
        rp0 = ent + (size_t)row0 * DIM;
        rp1 = ent + (size_t)row1 * DIM;
    } else if (row0 < n_ent + 2 * DIM) {
        const int k0 = row0 - n_ent;
        const int s = subject[0], r = relation[0];
        if (k0 < DIM) {
            m0 = ent[(size_t)s * DIM + k0];
            m1 = ent[(size_t)s * DIM + k0 + 1];
        } else {
            m0 = rel[(size_t)r * DIM + (k0 - DIM)];
            m1 = rel[(size_t)r * DIM + (k0 - DIM + 1)];
        }
        rp0 = Wq + (size_t)k0 * DIM;
        rp1 = rp0 + DIM;
    } else {                                   // bias pair (row1 may be invalid)
        rp0 = bq;
        rp1 = bq;
        m1 = 0.f;
    }

    // Needed Ws half only (lane->offset map identical for every row).
    const float* wsrc = is_ent ? (Ws + DIM) : Ws;
    float acc0 = 0.f, acc1 = 0.f;
#pragma unroll
    for (int it = 0; it < 4; ++it) {
        const int j = (it * 64 + lane) * 4;
        float4 w  = *(const float4*)(wsrc + j);
        float4 a0 = *(const float4*)(rp0 + j);
        float4 a1 = *(const float4*)(rp1 + j);
        acc0 += a0.x * w.x + a0.y * w.y + a0.z * w.z + a0.w * w.w;
        acc1 += a1.x * w.x + a1.y * w.y + a1.z * w.z + a1.w * w.w;
    }
    // Interleaved butterfly: two independent chains overlap latency.
#pragma unroll
    for (int off = 32; off; off >>= 1) {
        acc0 += __shfl_xor(acc0, off, 64);
        acc1 += __shfl_xor(acc1, off, 64);
    }
    if (lane == 0) {
        if (is_ent) {
            *(float2*)(escore + row0) = make_float2(acc0, acc1);   // row0 even: aligned
        } else if (row1 < nrows) {
            *(float2*)(qpart + (row0 - n_ent)) = make_float2(acc0 * m0, acc1 * m1);
        } else {
            qpart[row0 - n_ent] = acc0;                            // bias slot 2048
        }
    }
}

// 256 blocks x 256 threads, 2 candidates/thread.
__global__ void k_score(const int* __restrict__ cand,
                        const float* __restrict__ escore,
                        const float* __restrict__ qpart,
                        const float* __restrict__ bs,
                        float* __restrict__ out, int n) {
    const int tid  = threadIdx.x;
    const int wid  = tid >> 6;
    const int lane = tid & 63;
    __shared__ float swave[4];
    __shared__ float s_q;

    // All 256 threads reduce qpart[NQ] (fixed order -> deterministic).
    float v = 0.f;
    for (int i = tid; i < NQ; i += 256) v += qpart[i];
#pragma unroll
    for (int off = 32; off; off >>= 1) v += __shfl_xor(v, off, 64);
    if (lane == 0) swave[wid] = v;
    __syncthreads();
    if (tid == 0) s_q = swave[0] + swave[1] + swave[2] + swave[3] + bs[0];
    __syncthreads();
    const float q = s_q;

    const int i0 = (blockIdx.x * 256 + tid) * 2;
    if (i0 + 1 < n) {
        int2 c = *(const int2*)(cand + i0);
        float x0 = q + escore[c.x];
        float x1 = q + escore[c.y];
        float2 o;
        o.x = 1.f / (1.f + expf(-x0));
        o.y = 1.f / (1.f + expf(-x1));
        *(float2*)(out + i0) = o;
    }
}

extern "C" void kernel_launch(void* const* d_in, const int* in_sizes, int n_in,
                              void* d_out, int out_size, void* d_ws, size_t ws_size,
                              hipStream_t stream) {
    const int*   subject  = (const int*)d_in[0];
    const int*   relation = (const int*)d_in[1];
    const int*   cand     = (const int*)d_in[2];
    const float* ent      = (const float*)d_in[3];
    const float* rel      = (const float*)d_in[4];
    const float* Wq       = (const float*)d_in[5];
    const float* bq       = (const float*)d_in[6];
    const float* Ws       = (const float*)d_in[7];
    const float* bs       = (const float*)d_in[8];

    const int n_ent  = in_sizes[3] / DIM;            // 10000
    const int n_cand = in_sizes[2];                  // 131072

    float* qpart  = (float*)d_ws;                    // NQ floats
    float* escore = (float*)((char*)d_ws + 16384);   // n_ent floats

    const int nrows  = n_ent + 2 * DIM + 1;          // 12049
    const int npairs = (nrows + 1) / 2;              // 6025
    const int pblk   = (npairs + 3) / 4;             // 1507 blocks (4 waves each)

    k_prep<<<pblk, 256, 0, stream>>>(subject, relation, ent, rel, Wq, bq, Ws,
                                     qpart, escore, n_ent, nrows, npairs);
    k_score<<<256, 256, 0, stream>>>(cand, escore, qpart, bs,
                                     (float*)d_out, n_cand);
}